// Round 9
// baseline (763.531 us; speedup 1.0000x reference)
//
#include <hip/hip_runtime.h>
#include <hip/hip_fp16.h>

#define NN 100000
#define NE 800000
#define DD 128
#define NL 4
#define NG 512
#define NT 10
#define BN_EPS 1e-5f
#define SCAN_B 1024
#define CHUNK 4

typedef __attribute__((ext_vector_type(4))) float f32x4;
typedef __attribute__((ext_vector_type(8))) _Float16 f16x8;

__device__ __forceinline__ float atomAddF(float* p, float v) {
  return unsafeAtomicAdd(p, v);
}

// ---------------- aux setup: counts + fp16 tables (bemb3, Wf, aemb16) --------

__global__ __launch_bounds__(256) void aux_setup_kernel(
    const int* __restrict__ ei, int* __restrict__ degcnt,
    int* __restrict__ incnt, const int* __restrict__ batch,
    int* __restrict__ gcount, const float* __restrict__ bond_emb,
    __half2* __restrict__ bemb3, const float* __restrict__ W,
    __half* __restrict__ Wf, const float* __restrict__ atom_emb,
    __half* __restrict__ aemb16) {
  const int idx = blockIdx.x * 256 + threadIdx.x;
  // job A: edge degree counts
  if (idx < NE) {
    atomicAdd(&degcnt[ei[idx]], 1);
    atomicAdd(&incnt[ei[NE + idx]], 1);
  }
  // job B: batch counts
  if (idx < NN) atomicAdd(&gcount[batch[idx]], 1);
  // job C: combined bond table bemb3[l][idx9][64] (half2)
  if (idx < NL * 512 * 64) {
    int lane = idx & 63;
    int c9 = (idx >> 6) & 511;
    int l = idx >> 15;
    int a0 = c9 & 7, a1 = (c9 >> 3) & 7, a2 = (c9 >> 6) & 7;
    const float* bl = bond_emb + l * 3 * 8 * DD;
    float2 v0 = *reinterpret_cast<const float2*>(&bl[a0 * DD + 2 * lane]);
    float2 v1 = *reinterpret_cast<const float2*>(&bl[(8 + a1) * DD + 2 * lane]);
    float2 v2 = *reinterpret_cast<const float2*>(&bl[(16 + a2) * DD + 2 * lane]);
    bemb3[idx] = __floats2half2_rn(v0.x + v1.x + v2.x, v0.y + v1.y + v2.y);
  }
  // job D: W -> fragment-ordered fp16
  if (idx < NL * 8 * 4 * 64) {
    int lane = idx & 63;
    int c = (idx >> 6) & 3;
    int t = (idx >> 8) & 7;
    int l = idx >> 11;
    const float* Wl = W + l * DD * DD;
    __half* o = Wf + idx * 8;
    int n = t * 16 + (lane & 15);
    int k0 = c * 32 + (lane >> 4) * 8;
#pragma unroll
    for (int i = 0; i < 8; ++i) o[i] = (__half)Wl[(k0 + i) * DD + n];
  }
  // job E: atom_emb -> fp16 copy (9*64*128 elems, 4 per thread)
  if (idx < 9 * 64 * 32) {
    float4 v = *reinterpret_cast<const float4*>(&atom_emb[idx * 4]);
    union { __half2 hh[2]; int2 i2; } u;
    u.hh[0] = __floats2half2_rn(v.x, v.y);
    u.hh[1] = __floats2half2_rn(v.z, v.w);
    *reinterpret_cast<int2*>(&aemb16[idx * 4]) = u.i2;
  }
}

// ---------------- atom encoder: h = sum of 9 fp16 table rows ----------------
// 16 threads/node, 8 ch each; x staged in LDS per 16-node block.

__global__ __launch_bounds__(256) void atom_encoder_kernel(
    const int* __restrict__ x, const __half* __restrict__ aemb16,
    __half* __restrict__ h) {
  __shared__ int xs[16 * 9];
  const int nb = blockIdx.x * 16;
  const int t = threadIdx.x;
  if (t < 144) {
    int gi = nb * 9 + t;
    xs[t] = (gi < NN * 9) ? x[gi] : 0;
  }
  __syncthreads();
  const int n = nb + (t >> 4);
  const int q8 = t & 15;
  if (n >= NN) return;
  const f16x8* av = reinterpret_cast<const f16x8*>(aemb16);
  float acc[8] = {};
#pragma unroll
  for (int f = 0; f < 9; ++f) {
    int r = xs[(t >> 4) * 9 + f];
    f16x8 v = av[(f * 64 + r) * 16 + q8];
#pragma unroll
    for (int i = 0; i < 8; ++i) acc[i] += (float)v[i];
  }
  union { __half2 hh[4]; int4 i4; } u;
#pragma unroll
  for (int i = 0; i < 4; ++i)
    u.hh[i] = __floats2half2_rn(acc[2 * i], acc[2 * i + 1]);
  *reinterpret_cast<int4*>(&h[n * DD + q8 * 8]) = u.i4;
}

// ---------------- CSR build (+deg_fin in scan1, +gscan in scan2) ----------------

__global__ __launch_bounds__(256) void scan1_kernel(
    const int* __restrict__ in, int* __restrict__ out, int* __restrict__ bsum,
    const int* __restrict__ degcnt, float* __restrict__ degrecip,
    float* __restrict__ dinv, int n) {
  __shared__ int s[256];
  int base = blockIdx.x * SCAN_B + threadIdx.x * 4;
  int v[4] = {0, 0, 0, 0};
  if (base + 3 < n) {
    int4 t = *reinterpret_cast<const int4*>(&in[base]);
    v[0] = t.x; v[1] = t.y; v[2] = t.z; v[3] = t.w;
  } else {
    for (int i = 0; i < 4; ++i) v[i] = (base + i < n) ? in[base + i] : 0;
  }
  for (int i = 0; i < 4; ++i) {
    if (base + i < n) {
      float dv = (float)degcnt[base + i] + 1.f;
      degrecip[base + i] = 1.f / dv;
      dinv[base + i] = rsqrtf(dv);
    }
  }
  int tsum = v[0] + v[1] + v[2] + v[3];
  s[threadIdx.x] = tsum;
  __syncthreads();
  for (int d = 1; d < 256; d <<= 1) {
    int t = (threadIdx.x >= d) ? s[threadIdx.x - d] : 0;
    __syncthreads();
    s[threadIdx.x] += t;
    __syncthreads();
  }
  int run = s[threadIdx.x] - tsum;
  if (threadIdx.x == 255) bsum[blockIdx.x] = s[255];
  for (int i = 0; i < 4; ++i) {
    if (base + i < n) out[base + i] = run;
    run += v[i];
  }
}

__global__ __launch_bounds__(512) void scan2_kernel(int* bsum, int nb,
                                                    const int* __restrict__ gcount,
                                                    int* __restrict__ gstart) {
  __shared__ int s[128];
  __shared__ int sg[NG];
  const int t = threadIdx.x;
  int v = 0;
  if (t < 128) {
    v = (t < nb) ? bsum[t] : 0;
    s[t] = v;
  }
  __syncthreads();
  for (int d = 1; d < 128; d <<= 1) {
    int tv = (t < 128 && t >= d) ? s[t - d] : 0;
    __syncthreads();
    if (t < 128) s[t] += tv;
    __syncthreads();
  }
  if (t < 128 && t < nb) bsum[t] = s[t] - v;
  int gv = gcount[t];
  sg[t] = gv;
  __syncthreads();
  for (int d = 1; d < NG; d <<= 1) {
    int tv = (t >= d) ? sg[t - d] : 0;
    __syncthreads();
    sg[t] += tv;
    __syncthreads();
  }
  gstart[t] = sg[t] - gv;
  if (t == NG - 1) gstart[NG] = sg[NG - 1];
}

__global__ __launch_bounds__(256) void scan3_kernel(int* off, const int* bsum,
                                                    int n, int total) {
  int i = blockIdx.x * 256 + threadIdx.x;
  if (i < n) off[i] += bsum[i / SCAN_B];
  if (i == 0) off[n] = total;
}

// packed edge record: {src(17b) | idx9<<17, norm_bits}
__global__ __launch_bounds__(256) void csr_fill_kernel(
    const int* __restrict__ ei, const int* __restrict__ eattr,
    const float* __restrict__ dinv, const int* __restrict__ off,
    int* __restrict__ cursor, int2* __restrict__ edata) {
  int e = blockIdx.x * 256 + threadIdx.x;
  if (e >= NE) return;
  int r = ei[e], c = ei[NE + e];
  int pos = atomicAdd(&cursor[c], 1);
  float nm = dinv[r] * dinv[c];
  int idx9 = eattr[e * 3] | (eattr[e * 3 + 1] << 3) | (eattr[e * 3 + 2] << 6);
  int2 d;
  d.x = r | (idx9 << 17);
  d.y = __float_as_int(nm);
  edata[off[c] + pos] = d;
}

// ---------------- MFMA GEMM: hl = act(A) @ W + bias (fp16 in/out) ----------------

__global__ __launch_bounds__(256) void gemm_mfma_kernel(
    const __half* __restrict__ A, const __half* __restrict__ Wf,
    const float* __restrict__ bias, const float* __restrict__ bn_scale,
    const float* __restrict__ bn_shift, int fuse_bn, __half* __restrict__ hl) {
  const int wid = threadIdx.x >> 6, lane = threadIdx.x & 63;
  const int r0 = blockIdx.x * 64 + wid * 16;
  const int arow = min(r0 + (lane & 15), NN - 1);
  const int kb = (lane >> 4) * 8;

  f16x8 afrag[4];
#pragma unroll
  for (int c = 0; c < 4; ++c) {
    const int k0 = c * 32 + kb;
    f16x8 raw = *reinterpret_cast<const f16x8*>(&A[arow * DD + k0]);
    if (fuse_bn) {
#pragma unroll
      for (int i = 0; i < 8; ++i) {
        float v = fmaxf((float)raw[i] * bn_scale[k0 + i] + bn_shift[k0 + i], 0.f);
        raw[i] = (_Float16)v;
      }
    }
    afrag[c] = raw;
  }

  f32x4 acc[8];
#pragma unroll
  for (int t = 0; t < 8; ++t) acc[t] = (f32x4){0.f, 0.f, 0.f, 0.f};

  const f16x8* __restrict__ wf = reinterpret_cast<const f16x8*>(Wf);
#pragma unroll
  for (int t = 0; t < 8; ++t) {
#pragma unroll
    for (int c = 0; c < 4; ++c) {
      f16x8 b = wf[(t * 4 + c) * 64 + lane];
      acc[t] = __builtin_amdgcn_mfma_f32_16x16x32_f16(afrag[c], b, acc[t], 0, 0, 0);
    }
  }

  const int colb = lane & 15;
  const int rbase = r0 + (lane >> 4) * 4;
#pragma unroll
  for (int t = 0; t < 8; ++t) {
    float bb = bias[t * 16 + colb];
#pragma unroll
    for (int j = 0; j < 4; ++j) {
      int row = rbase + j;
      if (row < NN) hl[row * DD + t * 16 + colb] = (__half)(acc[t][j] + bb);
    }
  }
}

// ---------------- fused gather + update + BN stats / pool ----------------

#define PROC(PX, PY)                                            \
  {                                                             \
    int p_ = (PX);                                              \
    float nm_ = __int_as_float(PY);                             \
    float2 hv_ = __half22float2(hl2[(p_ & 0x1FFFF) * 64 + lane]); \
    float2 be_ = __half22float2(bemb3[((p_ >> 17) & 0x1FF) * 64 + lane]); \
    acc0 += nm_ * fmaxf(hv_.x + be_.x, 0.f);                    \
    acc1 += nm_ * fmaxf(hv_.y + be_.y, 0.f);                    \
  }

__global__ __launch_bounds__(512) void gather_update_kernel(
    const int* __restrict__ off, const int2* __restrict__ edata,
    const __half2* __restrict__ hl2, const __half2* __restrict__ bemb3,
    const float* __restrict__ root, const float* __restrict__ degrecip,
    const int* __restrict__ batch, __half2* __restrict__ h2,
    float* __restrict__ hg, float* __restrict__ bn_sum,
    float* __restrict__ bn_sq, int mode) {  // mode 0: h+stats, 1: pool
  const int wid = threadIdx.x >> 6;
  const int lane = threadIdx.x & 63;
  float2 rt = *reinterpret_cast<const float2*>(&root[2 * lane]);
  __shared__ float s0[DD], s1[DD];
  if (mode == 0) {
    if (threadIdx.x < DD) { s0[threadIdx.x] = 0.f; s1[threadIdx.x] = 0.f; }
    __syncthreads();
  }
  float ls0 = 0, ls1 = 0, lq0 = 0, lq1 = 0;
  const int wv = blockIdx.x * 8 + wid;
  const int n0 = wv * CHUNK;
  const int n1 = min(n0 + CHUNK, NN);
  int curg = -1;
  float pg0 = 0.f, pg1 = 0.f;
  for (int n = n0; n < n1; ++n) {
    int k0 = off[n], k1 = off[n + 1];
    float acc0 = 0.f, acc1 = 0.f;
    int k = k0;
    for (; k + 3 < k1; k += 4) {
      int2 e0 = edata[k], e1 = edata[k + 1], e2 = edata[k + 2],
           e3 = edata[k + 3];
      PROC(e0.x, e0.y) PROC(e1.x, e1.y) PROC(e2.x, e2.y) PROC(e3.x, e3.y)
    }
    for (; k < k1; ++k) {
      int2 e0 = edata[k];
      PROC(e0.x, e0.y)
    }
    float dr = degrecip[n];
    float2 hs = __half22float2(hl2[n * 64 + lane]);
    float v0 = acc0 + fmaxf(hs.x + rt.x, 0.f) * dr;
    float v1 = acc1 + fmaxf(hs.y + rt.y, 0.f) * dr;
    if (mode == 0) {
      h2[n * 64 + lane] = __floats2half2_rn(v0, v1);
      ls0 += v0; ls1 += v1;
      lq0 += v0 * v0; lq1 += v1 * v1;
    } else {
      int g = batch[n];
      if (g != curg) {
        if (curg >= 0) {
          atomAddF(&hg[curg * DD + 2 * lane], pg0);
          atomAddF(&hg[curg * DD + 2 * lane + 1], pg1);
        }
        curg = g;
        pg0 = v0; pg1 = v1;
      } else {
        pg0 += v0; pg1 += v1;
      }
    }
  }
  if (mode == 0) {
    atomicAdd(&s0[2 * lane], ls0);
    atomicAdd(&s0[2 * lane + 1], ls1);
    atomicAdd(&s1[2 * lane], lq0);
    atomicAdd(&s1[2 * lane + 1], lq1);
    __syncthreads();
    if (threadIdx.x < DD) {
      atomAddF(&bn_sum[threadIdx.x], s0[threadIdx.x]);
      atomAddF(&bn_sq[threadIdx.x], s1[threadIdx.x]);
    }
  } else {
    if (curg >= 0) {
      atomAddF(&hg[curg * DD + 2 * lane], pg0);
      atomAddF(&hg[curg * DD + 2 * lane + 1], pg1);
    }
  }
}

__global__ __launch_bounds__(128) void bn_finalize_kernel(
    const float* __restrict__ bn_sum, const float* __restrict__ bn_sq,
    const float* __restrict__ gamma, const float* __restrict__ beta,
    float* __restrict__ scale, float* __restrict__ shift) {
  int d = threadIdx.x;
  float mu = bn_sum[d] / (float)NN;
  float var = bn_sq[d] / (float)NN - mu * mu;
  float inv = rsqrtf(var + BN_EPS);
  float sc = gamma[d] * inv;
  scale[d] = sc;
  shift[d] = beta[d] - mu * sc;
}

// ---------------- MLP on pooled features ----------------

__global__ __launch_bounds__(128) void mlp_kernel(
    const float* __restrict__ hg, const int* __restrict__ gstart,
    const float* __restrict__ W1, const float* __restrict__ b1,
    const float* __restrict__ W2, const float* __restrict__ b2,
    float* __restrict__ out) {
  int g = blockIdx.x, t = threadIdx.x;
  float cnt = fmaxf((float)(gstart[g + 1] - gstart[g]), 1.f);
  __shared__ float row[DD], t1[DD];
  row[t] = fmaxf(hg[g * DD + t] / cnt, 0.f);
  __syncthreads();
  float a1v = b1[t];
  for (int k = 0; k < DD; ++k) a1v = fmaf(row[k], W1[k * DD + t], a1v);
  t1[t] = fmaxf(a1v, 0.f);
  __syncthreads();
  if (t < NT) {
    float a2 = b2[t];
    for (int k = 0; k < DD; ++k) a2 = fmaf(t1[k], W2[k * NT + t], a2);
    out[g * NT + t] = a2;
  }
}

extern "C" void kernel_launch(void* const* d_in, const int* in_sizes, int n_in,
                              void* d_out, int out_size, void* d_ws,
                              size_t ws_size, hipStream_t stream) {
  const int* x = (const int*)d_in[0];
  const int* edge_index = (const int*)d_in[1];
  const int* batch = (const int*)d_in[2];
  const int* edge_attr = (const int*)d_in[3];
  const float* atom_emb = (const float*)d_in[4];
  const float* W = (const float*)d_in[5];
  const float* b = (const float*)d_in[6];
  const float* root = (const float*)d_in[7];
  const float* bond_emb = (const float*)d_in[8];
  const float* gamma = (const float*)d_in[9];
  const float* beta = (const float*)d_in[10];
  const float* W1 = (const float*)d_in[11];
  const float* b1 = (const float*)d_in[12];
  const float* W2 = (const float*)d_in[13];
  const float* b2 = (const float*)d_in[14];
  float* out = (float*)d_out;

  char* ws = (char*)d_ws;
  size_t off_b = 0;
  auto alloc = [&](size_t bytes) {
    char* p = ws + off_b;
    off_b += (bytes + 255) & ~size_t(255);
    return p;
  };
  __half* h = (__half*)alloc(sizeof(__half) * NN * DD);
  __half* hl = (__half*)alloc(sizeof(__half) * NN * DD);
  int2* edata = (int2*)alloc(sizeof(int2) * NE);
  float* degrecip = (float*)alloc(sizeof(float) * NN);
  float* dinv = (float*)alloc(sizeof(float) * NN);
  int* off = (int*)alloc(sizeof(int) * (NN + 1));
  int* bsum = (int*)alloc(sizeof(int) * 128);
  float* bsc = (float*)alloc(sizeof(float) * DD);
  float* bsh = (float*)alloc(sizeof(float) * DD);
  int* gstart = (int*)alloc(sizeof(int) * (NG + 1));
  __half* Wf = (__half*)alloc(sizeof(__half) * NL * DD * DD);
  __half2* bemb3 = (__half2*)alloc(sizeof(__half2) * NL * 512 * 64);
  __half* aemb16 = (__half*)alloc(sizeof(__half) * 9 * 64 * DD);
  // ---- contiguous zero region ----
  char* zstart = ws + off_b;
  int* degcnt = (int*)alloc(sizeof(int) * NN);
  int* incnt = (int*)alloc(sizeof(int) * NN);
  int* cursor = (int*)alloc(sizeof(int) * NN);
  int* gcount = (int*)alloc(sizeof(int) * NG);
  float* hg = (float*)alloc(sizeof(float) * NG * DD);
  float* bnS = (float*)alloc(sizeof(float) * NL * DD);
  float* bnQ = (float*)alloc(sizeof(float) * NL * DD);
  size_t zbytes = (ws + off_b) - zstart;

  hipMemsetAsync(zstart, 0, zbytes, stream);

  aux_setup_kernel<<<(NE + 255) / 256, 256, 0, stream>>>(
      edge_index, degcnt, incnt, batch, gcount, bond_emb, bemb3, W, Wf,
      atom_emb, aemb16);
  atom_encoder_kernel<<<(NN * 16 + 255) / 256, 256, 0, stream>>>(x, aemb16, h);

  const int nb = (NN + SCAN_B - 1) / SCAN_B;  // 98
  scan1_kernel<<<nb, 256, 0, stream>>>(incnt, off, bsum, degcnt, degrecip,
                                       dinv, NN);
  scan2_kernel<<<1, 512, 0, stream>>>(bsum, nb, gcount, gstart);
  scan3_kernel<<<(NN + 255) / 256, 256, 0, stream>>>(off, bsum, NN, NE);
  csr_fill_kernel<<<(NE + 255) / 256, 256, 0, stream>>>(edge_index, edge_attr,
                                                        dinv, off, cursor, edata);

  const int GB = (NN + 8 * CHUNK - 1) / (8 * CHUNK);  // 3125 blocks
  for (int l = 0; l < NL; ++l) {
    gemm_mfma_kernel<<<(NN + 63) / 64, 256, 0, stream>>>(
        h, Wf + l * DD * DD, b + l * DD, bsc, bsh, l > 0 ? 1 : 0, hl);
    int mode = (l < NL - 1) ? 0 : 1;
    gather_update_kernel<<<GB, 512, 0, stream>>>(
        off, edata, (const __half2*)hl, bemb3 + l * 512 * 64, root + l * DD,
        degrecip, batch, (__half2*)h, hg, bnS + l * DD, bnQ + l * DD, mode);
    if (mode == 0) {
      bn_finalize_kernel<<<1, DD, 0, stream>>>(bnS + l * DD, bnQ + l * DD,
                                               gamma + l * DD, beta + l * DD,
                                               bsc, bsh);
    }
  }

  mlp_kernel<<<NG, DD, 0, stream>>>(hg, gstart, W1, b1, W2, b2, out);
}

// Round 10
// 699.799 us; speedup vs baseline: 1.0911x; 1.0911x over previous
//
#include <hip/hip_runtime.h>
#include <hip/hip_fp16.h>

#define NN 100000
#define NE 800000
#define DD 128
#define NL 4
#define NG 512
#define NT 10
#define BN_EPS 1e-5f
#define SCAN_B 1024
#define CHUNK 4

typedef __attribute__((ext_vector_type(4))) float f32x4;
typedef __attribute__((ext_vector_type(8))) _Float16 f16x8;

__device__ __forceinline__ float atomAddF(float* p, float v) {
  return unsafeAtomicAdd(p, v);
}

// ---------------- edge degree counts (isolated: pure atomics) ----------------

__global__ __launch_bounds__(256) void edge_count_kernel(
    const int* __restrict__ ei, int* __restrict__ degcnt,
    int* __restrict__ incnt) {
  int t = blockIdx.x * 256 + threadIdx.x;
  if (t * 4 >= NE) return;
  int4 s = *reinterpret_cast<const int4*>(&ei[t * 4]);
  int4 d = *reinterpret_cast<const int4*>(&ei[NE + t * 4]);
  atomicAdd(&degcnt[s.x], 1);
  atomicAdd(&degcnt[s.y], 1);
  atomicAdd(&degcnt[s.z], 1);
  atomicAdd(&degcnt[s.w], 1);
  atomicAdd(&incnt[d.x], 1);
  atomicAdd(&incnt[d.y], 1);
  atomicAdd(&incnt[d.z], 1);
  atomicAdd(&incnt[d.w], 1);
}

// ---------------- tables: bemb3 + Wf + aemb16 + gstart (binary search) -------

__global__ __launch_bounds__(256) void tables_kernel(
    const float* __restrict__ bond_emb, __half2* __restrict__ bemb3,
    const float* __restrict__ W, __half* __restrict__ Wf,
    const float* __restrict__ atom_emb, __half* __restrict__ aemb16,
    const int* __restrict__ batch, int* __restrict__ gstart) {
  const int idx = blockIdx.x * 256 + threadIdx.x;
  // combined bond table bemb3[l][idx9][64] (half2)
  if (idx < NL * 512 * 64) {
    int lane = idx & 63;
    int c9 = (idx >> 6) & 511;
    int l = idx >> 15;
    int a0 = c9 & 7, a1 = (c9 >> 3) & 7, a2 = (c9 >> 6) & 7;
    const float* bl = bond_emb + l * 3 * 8 * DD;
    float2 v0 = *reinterpret_cast<const float2*>(&bl[a0 * DD + 2 * lane]);
    float2 v1 = *reinterpret_cast<const float2*>(&bl[(8 + a1) * DD + 2 * lane]);
    float2 v2 = *reinterpret_cast<const float2*>(&bl[(16 + a2) * DD + 2 * lane]);
    bemb3[idx] = __floats2half2_rn(v0.x + v1.x + v2.x, v0.y + v1.y + v2.y);
  }
  // W -> fragment-ordered fp16
  if (idx < NL * 8 * 4 * 64) {
    int lane = idx & 63;
    int c = (idx >> 6) & 3;
    int t = (idx >> 8) & 7;
    int l = idx >> 11;
    const float* Wl = W + l * DD * DD;
    __half* o = Wf + idx * 8;
    int n = t * 16 + (lane & 15);
    int k0 = c * 32 + (lane >> 4) * 8;
#pragma unroll
    for (int i = 0; i < 8; ++i) o[i] = (__half)Wl[(k0 + i) * DD + n];
  }
  // atom_emb -> fp16
  if (idx < 9 * 64 * 32) {
    float4 v = *reinterpret_cast<const float4*>(&atom_emb[idx * 4]);
    union { __half2 hh[2]; int2 i2; } u;
    u.hh[0] = __floats2half2_rn(v.x, v.y);
    u.hh[1] = __floats2half2_rn(v.z, v.w);
    *reinterpret_cast<int2*>(&aemb16[idx * 4]) = u.i2;
  }
  // gstart via binary search over sorted batch
  if (idx <= NG) {
    if (idx == NG) {
      gstart[NG] = NN;
    } else {
      int lo = 0, hi = NN;
      while (lo < hi) {
        int m = (lo + hi) >> 1;
        if (batch[m] < idx) lo = m + 1; else hi = m;
      }
      gstart[idx] = lo;
    }
  }
}

// ---------------- atom encoder ----------------

__global__ __launch_bounds__(256) void atom_encoder_kernel(
    const int* __restrict__ x, const __half* __restrict__ aemb16,
    __half* __restrict__ h) {
  __shared__ int xs[16 * 9];
  const int nb = blockIdx.x * 16;
  const int t = threadIdx.x;
  if (t < 144) {
    int gi = nb * 9 + t;
    xs[t] = (gi < NN * 9) ? x[gi] : 0;
  }
  __syncthreads();
  const int n = nb + (t >> 4);
  const int q8 = t & 15;
  if (n >= NN) return;
  const f16x8* av = reinterpret_cast<const f16x8*>(aemb16);
  float acc[8] = {};
#pragma unroll
  for (int f = 0; f < 9; ++f) {
    int r = xs[(t >> 4) * 9 + f];
    f16x8 v = av[(f * 64 + r) * 16 + q8];
#pragma unroll
    for (int i = 0; i < 8; ++i) acc[i] += (float)v[i];
  }
  union { __half2 hh[4]; int4 i4; } u;
#pragma unroll
  for (int i = 0; i < 4; ++i)
    u.hh[i] = __floats2half2_rn(acc[2 * i], acc[2 * i + 1]);
  *reinterpret_cast<int4*>(&h[n * DD + q8 * 8]) = u.i4;
}

// ---------------- CSR build ----------------

__global__ __launch_bounds__(256) void scan1_kernel(
    const int* __restrict__ in, int* __restrict__ out, int* __restrict__ bsum,
    const int* __restrict__ degcnt, float* __restrict__ degrecip,
    float* __restrict__ dinv, int n) {
  __shared__ int s[256];
  int base = blockIdx.x * SCAN_B + threadIdx.x * 4;
  int v[4] = {0, 0, 0, 0};
  if (base + 3 < n) {
    int4 t = *reinterpret_cast<const int4*>(&in[base]);
    v[0] = t.x; v[1] = t.y; v[2] = t.z; v[3] = t.w;
  } else {
    for (int i = 0; i < 4; ++i) v[i] = (base + i < n) ? in[base + i] : 0;
  }
  for (int i = 0; i < 4; ++i) {
    if (base + i < n) {
      float dv = (float)degcnt[base + i] + 1.f;
      degrecip[base + i] = 1.f / dv;
      dinv[base + i] = rsqrtf(dv);
    }
  }
  int tsum = v[0] + v[1] + v[2] + v[3];
  s[threadIdx.x] = tsum;
  __syncthreads();
  for (int d = 1; d < 256; d <<= 1) {
    int t = (threadIdx.x >= d) ? s[threadIdx.x - d] : 0;
    __syncthreads();
    s[threadIdx.x] += t;
    __syncthreads();
  }
  int run = s[threadIdx.x] - tsum;
  if (threadIdx.x == 255) bsum[blockIdx.x] = s[255];
  for (int i = 0; i < 4; ++i) {
    if (base + i < n) out[base + i] = run;
    run += v[i];
  }
}

__global__ void scan2_kernel(int* bsum, int nb) {
  __shared__ int s[128];
  int v = (threadIdx.x < nb) ? bsum[threadIdx.x] : 0;
  s[threadIdx.x] = v;
  __syncthreads();
  for (int d = 1; d < 128; d <<= 1) {
    int t = (threadIdx.x >= d) ? s[threadIdx.x - d] : 0;
    __syncthreads();
    s[threadIdx.x] += t;
    __syncthreads();
  }
  if (threadIdx.x < nb) bsum[threadIdx.x] = s[threadIdx.x] - v;
}

__global__ __launch_bounds__(256) void scan3_kernel(int* off, const int* bsum,
                                                    int n, int total) {
  int i = blockIdx.x * 256 + threadIdx.x;
  if (i < n) off[i] += bsum[i / SCAN_B];
  if (i == 0) off[n] = total;
}

// packed edge record: {src(17b) | idx9<<17, norm_bits}
__global__ __launch_bounds__(256) void csr_fill_kernel(
    const int* __restrict__ ei, const int* __restrict__ eattr,
    const float* __restrict__ dinv, const int* __restrict__ off,
    int* __restrict__ cursor, int2* __restrict__ edata) {
  int e = blockIdx.x * 256 + threadIdx.x;
  if (e >= NE) return;
  int r = ei[e], c = ei[NE + e];
  int pos = atomicAdd(&cursor[c], 1);
  float nm = dinv[r] * dinv[c];
  int idx9 = eattr[e * 3] | (eattr[e * 3 + 1] << 3) | (eattr[e * 3 + 2] << 6);
  int2 d;
  d.x = r | (idx9 << 17);
  d.y = __float_as_int(nm);
  edata[off[c] + pos] = d;
}

// ---------------- MFMA GEMM: hl = act(A) @ W + bias (fp16 in/out) ----------------

__global__ __launch_bounds__(256) void gemm_mfma_kernel(
    const __half* __restrict__ A, const __half* __restrict__ Wf,
    const float* __restrict__ bias, const float* __restrict__ bn_scale,
    const float* __restrict__ bn_shift, int fuse_bn, __half* __restrict__ hl) {
  const int wid = threadIdx.x >> 6, lane = threadIdx.x & 63;
  const int r0 = blockIdx.x * 64 + wid * 16;
  const int arow = min(r0 + (lane & 15), NN - 1);
  const int kb = (lane >> 4) * 8;

  f16x8 afrag[4];
#pragma unroll
  for (int c = 0; c < 4; ++c) {
    const int k0 = c * 32 + kb;
    f16x8 raw = *reinterpret_cast<const f16x8*>(&A[arow * DD + k0]);
    if (fuse_bn) {
#pragma unroll
      for (int i = 0; i < 8; ++i) {
        float v = fmaxf((float)raw[i] * bn_scale[k0 + i] + bn_shift[k0 + i], 0.f);
        raw[i] = (_Float16)v;
      }
    }
    afrag[c] = raw;
  }

  f32x4 acc[8];
#pragma unroll
  for (int t = 0; t < 8; ++t) acc[t] = (f32x4){0.f, 0.f, 0.f, 0.f};

  const f16x8* __restrict__ wf = reinterpret_cast<const f16x8*>(Wf);
#pragma unroll
  for (int t = 0; t < 8; ++t) {
#pragma unroll
    for (int c = 0; c < 4; ++c) {
      f16x8 b = wf[(t * 4 + c) * 64 + lane];
      acc[t] = __builtin_amdgcn_mfma_f32_16x16x32_f16(afrag[c], b, acc[t], 0, 0, 0);
    }
  }

  const int colb = lane & 15;
  const int rbase = r0 + (lane >> 4) * 4;
#pragma unroll
  for (int t = 0; t < 8; ++t) {
    float bb = bias[t * 16 + colb];
#pragma unroll
    for (int j = 0; j < 4; ++j) {
      int row = rbase + j;
      if (row < NN) hl[row * DD + t * 16 + colb] = (__half)(acc[t][j] + bb);
    }
  }
}

// ---------------- fused gather + update + BN stats / pool ----------------
// software-pipelined: group B's edata+hl2+bemb3 loads issue under group A's FMAs

#define LOADH(E, HV, BV)                                 \
  {                                                      \
    int p_ = (E).x;                                      \
    HV = hl2[(p_ & 0x1FFFF) * 64 + lane];                \
    BV = bemb3[((p_ >> 17) & 0x1FF) * 64 + lane];        \
  }
#define COMP(E, HV, BV)                                  \
  {                                                      \
    float nm_ = __int_as_float((E).y);                   \
    float2 h_ = __half22float2(HV);                      \
    float2 b_ = __half22float2(BV);                      \
    acc0 += nm_ * fmaxf(h_.x + b_.x, 0.f);               \
    acc1 += nm_ * fmaxf(h_.y + b_.y, 0.f);               \
  }

__global__ __launch_bounds__(512) void gather_update_kernel(
    const int* __restrict__ off, const int2* __restrict__ edata,
    const __half2* __restrict__ hl2, const __half2* __restrict__ bemb3,
    const float* __restrict__ root, const float* __restrict__ degrecip,
    const int* __restrict__ batch, __half2* __restrict__ h2,
    float* __restrict__ hg, float* __restrict__ bn_sum,
    float* __restrict__ bn_sq, int mode) {  // mode 0: h+stats, 1: pool
  const int wid = threadIdx.x >> 6;
  const int lane = threadIdx.x & 63;
  float2 rt = *reinterpret_cast<const float2*>(&root[2 * lane]);
  __shared__ float s0[DD], s1[DD];
  if (mode == 0) {
    if (threadIdx.x < DD) { s0[threadIdx.x] = 0.f; s1[threadIdx.x] = 0.f; }
    __syncthreads();
  }
  float ls0 = 0, ls1 = 0, lq0 = 0, lq1 = 0;
  const int wv = blockIdx.x * 8 + wid;
  const int n0 = wv * CHUNK;
  const int n1 = min(n0 + CHUNK, NN);
  int curg = -1;
  float pg0 = 0.f, pg1 = 0.f;
  for (int n = n0; n < n1; ++n) {
    int k0 = off[n], k1 = off[n + 1];
    float acc0 = 0.f, acc1 = 0.f;
    int k = k0;
    if (k + 3 < k1) {
      int2 A0 = edata[k], A1 = edata[k + 1], A2 = edata[k + 2],
           A3 = edata[k + 3];
      __half2 ha0, ba0, ha1, ba1, ha2, ba2, ha3, ba3;
      LOADH(A0, ha0, ba0) LOADH(A1, ha1, ba1)
      LOADH(A2, ha2, ba2) LOADH(A3, ha3, ba3)
      k += 4;
      for (; k + 3 < k1; k += 4) {
        int2 B0 = edata[k], B1 = edata[k + 1], B2 = edata[k + 2],
             B3 = edata[k + 3];
        __half2 hb0, bb0, hb1, bb1, hb2, bb2, hb3, bb3;
        LOADH(B0, hb0, bb0) LOADH(B1, hb1, bb1)
        LOADH(B2, hb2, bb2) LOADH(B3, hb3, bb3)
        COMP(A0, ha0, ba0) COMP(A1, ha1, ba1)
        COMP(A2, ha2, ba2) COMP(A3, ha3, ba3)
        A0 = B0; A1 = B1; A2 = B2; A3 = B3;
        ha0 = hb0; ba0 = bb0; ha1 = hb1; ba1 = bb1;
        ha2 = hb2; ba2 = bb2; ha3 = hb3; ba3 = bb3;
      }
      COMP(A0, ha0, ba0) COMP(A1, ha1, ba1)
      COMP(A2, ha2, ba2) COMP(A3, ha3, ba3)
    }
    for (; k < k1; ++k) {
      int2 e0 = edata[k];
      __half2 hv, bv;
      LOADH(e0, hv, bv)
      COMP(e0, hv, bv)
    }
    float dr = degrecip[n];
    float2 hs = __half22float2(hl2[n * 64 + lane]);
    float v0 = acc0 + fmaxf(hs.x + rt.x, 0.f) * dr;
    float v1 = acc1 + fmaxf(hs.y + rt.y, 0.f) * dr;
    if (mode == 0) {
      h2[n * 64 + lane] = __floats2half2_rn(v0, v1);
      ls0 += v0; ls1 += v1;
      lq0 += v0 * v0; lq1 += v1 * v1;
    } else {
      int g = batch[n];
      if (g != curg) {
        if (curg >= 0) {
          atomAddF(&hg[curg * DD + 2 * lane], pg0);
          atomAddF(&hg[curg * DD + 2 * lane + 1], pg1);
        }
        curg = g;
        pg0 = v0; pg1 = v1;
      } else {
        pg0 += v0; pg1 += v1;
      }
    }
  }
  if (mode == 0) {
    atomicAdd(&s0[2 * lane], ls0);
    atomicAdd(&s0[2 * lane + 1], ls1);
    atomicAdd(&s1[2 * lane], lq0);
    atomicAdd(&s1[2 * lane + 1], lq1);
    __syncthreads();
    if (threadIdx.x < DD) {
      atomAddF(&bn_sum[threadIdx.x], s0[threadIdx.x]);
      atomAddF(&bn_sq[threadIdx.x], s1[threadIdx.x]);
    }
  } else {
    if (curg >= 0) {
      atomAddF(&hg[curg * DD + 2 * lane], pg0);
      atomAddF(&hg[curg * DD + 2 * lane + 1], pg1);
    }
  }
}

__global__ __launch_bounds__(128) void bn_finalize_kernel(
    const float* __restrict__ bn_sum, const float* __restrict__ bn_sq,
    const float* __restrict__ gamma, const float* __restrict__ beta,
    float* __restrict__ scale, float* __restrict__ shift) {
  int d = threadIdx.x;
  float mu = bn_sum[d] / (float)NN;
  float var = bn_sq[d] / (float)NN - mu * mu;
  float inv = rsqrtf(var + BN_EPS);
  float sc = gamma[d] * inv;
  scale[d] = sc;
  shift[d] = beta[d] - mu * sc;
}

// ---------------- MLP on pooled features ----------------

__global__ __launch_bounds__(128) void mlp_kernel(
    const float* __restrict__ hg, const int* __restrict__ gstart,
    const float* __restrict__ W1, const float* __restrict__ b1,
    const float* __restrict__ W2, const float* __restrict__ b2,
    float* __restrict__ out) {
  int g = blockIdx.x, t = threadIdx.x;
  float cnt = fmaxf((float)(gstart[g + 1] - gstart[g]), 1.f);
  __shared__ float row[DD], t1[DD];
  row[t] = fmaxf(hg[g * DD + t] / cnt, 0.f);
  __syncthreads();
  float a1v = b1[t];
  for (int k = 0; k < DD; ++k) a1v = fmaf(row[k], W1[k * DD + t], a1v);
  t1[t] = fmaxf(a1v, 0.f);
  __syncthreads();
  if (t < NT) {
    float a2 = b2[t];
    for (int k = 0; k < DD; ++k) a2 = fmaf(t1[k], W2[k * NT + t], a2);
    out[g * NT + t] = a2;
  }
}

extern "C" void kernel_launch(void* const* d_in, const int* in_sizes, int n_in,
                              void* d_out, int out_size, void* d_ws,
                              size_t ws_size, hipStream_t stream) {
  const int* x = (const int*)d_in[0];
  const int* edge_index = (const int*)d_in[1];
  const int* batch = (const int*)d_in[2];
  const int* edge_attr = (const int*)d_in[3];
  const float* atom_emb = (const float*)d_in[4];
  const float* W = (const float*)d_in[5];
  const float* b = (const float*)d_in[6];
  const float* root = (const float*)d_in[7];
  const float* bond_emb = (const float*)d_in[8];
  const float* gamma = (const float*)d_in[9];
  const float* beta = (const float*)d_in[10];
  const float* W1 = (const float*)d_in[11];
  const float* b1 = (const float*)d_in[12];
  const float* W2 = (const float*)d_in[13];
  const float* b2 = (const float*)d_in[14];
  float* out = (float*)d_out;

  char* ws = (char*)d_ws;
  size_t off_b = 0;
  auto alloc = [&](size_t bytes) {
    char* p = ws + off_b;
    off_b += (bytes + 255) & ~size_t(255);
    return p;
  };
  __half* h = (__half*)alloc(sizeof(__half) * NN * DD);
  __half* hl = (__half*)alloc(sizeof(__half) * NN * DD);
  int2* edata = (int2*)alloc(sizeof(int2) * NE);
  float* degrecip = (float*)alloc(sizeof(float) * NN);
  float* dinv = (float*)alloc(sizeof(float) * NN);
  int* off = (int*)alloc(sizeof(int) * (NN + 1));
  int* bsum = (int*)alloc(sizeof(int) * 128);
  float* bsc = (float*)alloc(sizeof(float) * DD);
  float* bsh = (float*)alloc(sizeof(float) * DD);
  int* gstart = (int*)alloc(sizeof(int) * (NG + 1));
  __half* Wf = (__half*)alloc(sizeof(__half) * NL * DD * DD);
  __half2* bemb3 = (__half2*)alloc(sizeof(__half2) * NL * 512 * 64);
  __half* aemb16 = (__half*)alloc(sizeof(__half) * 9 * 64 * DD);
  // ---- contiguous zero region ----
  char* zstart = ws + off_b;
  int* degcnt = (int*)alloc(sizeof(int) * NN);
  int* incnt = (int*)alloc(sizeof(int) * NN);
  int* cursor = (int*)alloc(sizeof(int) * NN);
  float* hg = (float*)alloc(sizeof(float) * NG * DD);
  float* bnS = (float*)alloc(sizeof(float) * NL * DD);
  float* bnQ = (float*)alloc(sizeof(float) * NL * DD);
  size_t zbytes = (ws + off_b) - zstart;

  hipMemsetAsync(zstart, 0, zbytes, stream);

  edge_count_kernel<<<(NE / 4 + 255) / 256, 256, 0, stream>>>(edge_index,
                                                              degcnt, incnt);
  tables_kernel<<<(NL * 512 * 64 + 255) / 256, 256, 0, stream>>>(
      bond_emb, bemb3, W, Wf, atom_emb, aemb16, batch, gstart);
  atom_encoder_kernel<<<(NN * 16 + 255) / 256, 256, 0, stream>>>(x, aemb16, h);

  const int nb = (NN + SCAN_B - 1) / SCAN_B;  // 98
  scan1_kernel<<<nb, 256, 0, stream>>>(incnt, off, bsum, degcnt, degrecip,
                                       dinv, NN);
  scan2_kernel<<<1, 128, 0, stream>>>(bsum, nb);
  scan3_kernel<<<(NN + 255) / 256, 256, 0, stream>>>(off, bsum, NN, NE);
  csr_fill_kernel<<<(NE + 255) / 256, 256, 0, stream>>>(edge_index, edge_attr,
                                                        dinv, off, cursor, edata);

  const int GB = (NN + 8 * CHUNK - 1) / (8 * CHUNK);  // 3125 blocks
  for (int l = 0; l < NL; ++l) {
    gemm_mfma_kernel<<<(NN + 63) / 64, 256, 0, stream>>>(
        h, Wf + l * DD * DD, b + l * DD, bsc, bsh, l > 0 ? 1 : 0, hl);
    int mode = (l < NL - 1) ? 0 : 1;
    gather_update_kernel<<<GB, 512, 0, stream>>>(
        off, edata, (const __half2*)hl, bemb3 + l * 512 * 64, root + l * DD,
        degrecip, batch, (__half2*)h, hg, bnS + l * DD, bnQ + l * DD, mode);
    if (mode == 0) {
      bn_finalize_kernel<<<1, DD, 0, stream>>>(bnS + l * DD, bnQ + l * DD,
                                               gamma + l * DD, beta + l * DD,
                                               bsc, bsh);
    }
  }

  mlp_kernel<<<NG, DD, 0, stream>>>(hg, gstart, W1, b1, W2, b2, out);
}

// Round 11
// 578.659 us; speedup vs baseline: 1.3195x; 1.2093x over previous
//
#include <hip/hip_runtime.h>
#include <hip/hip_fp16.h>

#define NN 100000
#define NE 800000
#define DD 128
#define NL 4
#define NG 512
#define NT 10
#define BN_EPS 1e-5f
#define SCAN_B 1024
#define CHUNK 13

typedef __attribute__((ext_vector_type(4))) float f32x4;
typedef __attribute__((ext_vector_type(8))) _Float16 f16x8;

__device__ __forceinline__ float atomAddF(float* p, float v) {
  return unsafeAtomicAdd(p, v);
}

// ---------------- edge degree counts (isolated: pure atomics) ----------------

__global__ __launch_bounds__(256) void edge_count_kernel(
    const int* __restrict__ ei, int* __restrict__ degcnt,
    int* __restrict__ incnt) {
  int t = blockIdx.x * 256 + threadIdx.x;
  if (t * 4 >= NE) return;
  int4 s = *reinterpret_cast<const int4*>(&ei[t * 4]);
  int4 d = *reinterpret_cast<const int4*>(&ei[NE + t * 4]);
  atomicAdd(&degcnt[s.x], 1);
  atomicAdd(&degcnt[s.y], 1);
  atomicAdd(&degcnt[s.z], 1);
  atomicAdd(&degcnt[s.w], 1);
  atomicAdd(&incnt[d.x], 1);
  atomicAdd(&incnt[d.y], 1);
  atomicAdd(&incnt[d.z], 1);
  atomicAdd(&incnt[d.w], 1);
}

// ---------------- tables: Wf + aemb16 + gstart (binary search) -------

__global__ __launch_bounds__(256) void tables_kernel(
    const float* __restrict__ W, __half* __restrict__ Wf,
    const float* __restrict__ atom_emb, __half* __restrict__ aemb16,
    const int* __restrict__ batch, int* __restrict__ gstart) {
  const int idx = blockIdx.x * 256 + threadIdx.x;
  // W -> fragment-ordered fp16
  if (idx < NL * 8 * 4 * 64) {
    int lane = idx & 63;
    int c = (idx >> 6) & 3;
    int t = (idx >> 8) & 7;
    int l = idx >> 11;
    const float* Wl = W + l * DD * DD;
    __half* o = Wf + idx * 8;
    int n = t * 16 + (lane & 15);
    int k0 = c * 32 + (lane >> 4) * 8;
#pragma unroll
    for (int i = 0; i < 8; ++i) o[i] = (__half)Wl[(k0 + i) * DD + n];
  }
  // atom_emb -> fp16
  if (idx < 9 * 64 * 32) {
    float4 v = *reinterpret_cast<const float4*>(&atom_emb[idx * 4]);
    union { __half2 hh[2]; int2 i2; } u;
    u.hh[0] = __floats2half2_rn(v.x, v.y);
    u.hh[1] = __floats2half2_rn(v.z, v.w);
    *reinterpret_cast<int2*>(&aemb16[idx * 4]) = u.i2;
  }
  // gstart via binary search over sorted batch
  if (idx <= NG) {
    if (idx == NG) {
      gstart[NG] = NN;
    } else {
      int lo = 0, hi = NN;
      while (lo < hi) {
        int m = (lo + hi) >> 1;
        if (batch[m] < idx) lo = m + 1; else hi = m;
      }
      gstart[idx] = lo;
    }
  }
}

// ---------------- atom encoder ----------------

__global__ __launch_bounds__(256) void atom_encoder_kernel(
    const int* __restrict__ x, const __half* __restrict__ aemb16,
    __half* __restrict__ h) {
  __shared__ int xs[16 * 9];
  const int nb = blockIdx.x * 16;
  const int t = threadIdx.x;
  if (t < 144) {
    int gi = nb * 9 + t;
    xs[t] = (gi < NN * 9) ? x[gi] : 0;
  }
  __syncthreads();
  const int n = nb + (t >> 4);
  const int q8 = t & 15;
  if (n >= NN) return;
  const f16x8* av = reinterpret_cast<const f16x8*>(aemb16);
  float acc[8] = {};
#pragma unroll
  for (int f = 0; f < 9; ++f) {
    int r = xs[(t >> 4) * 9 + f];
    f16x8 v = av[(f * 64 + r) * 16 + q8];
#pragma unroll
    for (int i = 0; i < 8; ++i) acc[i] += (float)v[i];
  }
  union { __half2 hh[4]; int4 i4; } u;
#pragma unroll
  for (int i = 0; i < 4; ++i)
    u.hh[i] = __floats2half2_rn(acc[2 * i], acc[2 * i + 1]);
  *reinterpret_cast<int4*>(&h[n * DD + q8 * 8]) = u.i4;
}

// ---------------- CSR build ----------------

__global__ __launch_bounds__(256) void scan1_kernel(
    const int* __restrict__ in, int* __restrict__ out, int* __restrict__ bsum,
    const int* __restrict__ degcnt, float* __restrict__ degrecip,
    float* __restrict__ dinv, int n) {
  __shared__ int s[256];
  int base = blockIdx.x * SCAN_B + threadIdx.x * 4;
  int v[4] = {0, 0, 0, 0};
  if (base + 3 < n) {
    int4 t = *reinterpret_cast<const int4*>(&in[base]);
    v[0] = t.x; v[1] = t.y; v[2] = t.z; v[3] = t.w;
  } else {
    for (int i = 0; i < 4; ++i) v[i] = (base + i < n) ? in[base + i] : 0;
  }
  for (int i = 0; i < 4; ++i) {
    if (base + i < n) {
      float dv = (float)degcnt[base + i] + 1.f;
      degrecip[base + i] = 1.f / dv;
      dinv[base + i] = rsqrtf(dv);
    }
  }
  int tsum = v[0] + v[1] + v[2] + v[3];
  s[threadIdx.x] = tsum;
  __syncthreads();
  for (int d = 1; d < 256; d <<= 1) {
    int t = (threadIdx.x >= d) ? s[threadIdx.x - d] : 0;
    __syncthreads();
    s[threadIdx.x] += t;
    __syncthreads();
  }
  int run = s[threadIdx.x] - tsum;
  if (threadIdx.x == 255) bsum[blockIdx.x] = s[255];
  for (int i = 0; i < 4; ++i) {
    if (base + i < n) out[base + i] = run;
    run += v[i];
  }
}

__global__ void scan2_kernel(int* bsum, int nb) {
  __shared__ int s[128];
  int v = (threadIdx.x < nb) ? bsum[threadIdx.x] : 0;
  s[threadIdx.x] = v;
  __syncthreads();
  for (int d = 1; d < 128; d <<= 1) {
    int t = (threadIdx.x >= d) ? s[threadIdx.x - d] : 0;
    __syncthreads();
    s[threadIdx.x] += t;
    __syncthreads();
  }
  if (threadIdx.x < nb) bsum[threadIdx.x] = s[threadIdx.x] - v;
}

__global__ __launch_bounds__(256) void scan3_kernel(int* off, const int* bsum,
                                                    int n, int total) {
  int i = blockIdx.x * 256 + threadIdx.x;
  if (i < n) off[i] += bsum[i / SCAN_B];
  if (i == 0) off[n] = total;
}

// packed edge record: {src(17b) | idx9<<17, norm_bits}
__global__ __launch_bounds__(256) void csr_fill_kernel(
    const int* __restrict__ ei, const int* __restrict__ eattr,
    const float* __restrict__ dinv, const int* __restrict__ off,
    int* __restrict__ cursor, int2* __restrict__ edata) {
  int e = blockIdx.x * 256 + threadIdx.x;
  if (e >= NE) return;
  int r = ei[e], c = ei[NE + e];
  int pos = atomicAdd(&cursor[c], 1);
  float nm = dinv[r] * dinv[c];
  int idx9 = eattr[e * 3] | (eattr[e * 3 + 1] << 3) | (eattr[e * 3 + 2] << 6);
  int2 d;
  d.x = r | (idx9 << 17);
  d.y = __float_as_int(nm);
  edata[off[c] + pos] = d;
}

// ---------------- MFMA GEMM: hl = act(A) @ W + bias (fp16 in/out) ----------------

__global__ __launch_bounds__(256) void gemm_mfma_kernel(
    const __half* __restrict__ A, const __half* __restrict__ Wf,
    const float* __restrict__ bias, const float* __restrict__ bn_scale,
    const float* __restrict__ bn_shift, int fuse_bn, __half* __restrict__ hl) {
  const int wid = threadIdx.x >> 6, lane = threadIdx.x & 63;
  const int r0 = blockIdx.x * 64 + wid * 16;
  const int arow = min(r0 + (lane & 15), NN - 1);
  const int kb = (lane >> 4) * 8;

  f16x8 afrag[4];
#pragma unroll
  for (int c = 0; c < 4; ++c) {
    const int k0 = c * 32 + kb;
    f16x8 raw = *reinterpret_cast<const f16x8*>(&A[arow * DD + k0]);
    if (fuse_bn) {
#pragma unroll
      for (int i = 0; i < 8; ++i) {
        float v = fmaxf((float)raw[i] * bn_scale[k0 + i] + bn_shift[k0 + i], 0.f);
        raw[i] = (_Float16)v;
      }
    }
    afrag[c] = raw;
  }

  f32x4 acc[8];
#pragma unroll
  for (int t = 0; t < 8; ++t) acc[t] = (f32x4){0.f, 0.f, 0.f, 0.f};

  const f16x8* __restrict__ wf = reinterpret_cast<const f16x8*>(Wf);
#pragma unroll
  for (int t = 0; t < 8; ++t) {
#pragma unroll
    for (int c = 0; c < 4; ++c) {
      f16x8 b = wf[(t * 4 + c) * 64 + lane];
      acc[t] = __builtin_amdgcn_mfma_f32_16x16x32_f16(afrag[c], b, acc[t], 0, 0, 0);
    }
  }

  const int colb = lane & 15;
  const int rbase = r0 + (lane >> 4) * 4;
#pragma unroll
  for (int t = 0; t < 8; ++t) {
    float bb = bias[t * 16 + colb];
#pragma unroll
    for (int j = 0; j < 4; ++j) {
      int row = rbase + j;
      if (row < NN) hl[row * DD + t * 16 + colb] = (__half)(acc[t][j] + bb);
    }
  }
}

// ---------------- fused gather + update + BN stats / pool ----------------
// R4-proven shape: 256 thr, 4 waves, CHUNK=13, fp32 bond table in LDS (12KB),
// one VMEM stream per edge (hl2), simple 4x unroll. fp16 h write.

#define PROC(E)                                                   \
  {                                                               \
    int p_ = (E).x;                                               \
    float nm_ = __int_as_float((E).y);                            \
    float2 hv_ = __half22float2(hl2[(p_ & 0x1FFFF) * 64 + lane]); \
    int i9_ = p_ >> 17;                                           \
    float2 b0_ = bembS[(i9_ & 7) * 64 + lane];                    \
    float2 b1_ = bembS[(8 + ((i9_ >> 3) & 7)) * 64 + lane];       \
    float2 b2_ = bembS[(16 + ((i9_ >> 6) & 7)) * 64 + lane];      \
    acc0 += nm_ * fmaxf(hv_.x + b0_.x + b1_.x + b2_.x, 0.f);      \
    acc1 += nm_ * fmaxf(hv_.y + b0_.y + b1_.y + b2_.y, 0.f);      \
  }

__global__ __launch_bounds__(256) void gather_update_kernel(
    const int* __restrict__ off, const int2* __restrict__ edata,
    const __half2* __restrict__ hl2, const float* __restrict__ bemb,
    const float* __restrict__ root, const float* __restrict__ degrecip,
    const int* __restrict__ batch, __half2* __restrict__ h2,
    float* __restrict__ hg, float* __restrict__ bn_sum,
    float* __restrict__ bn_sq, int mode) {  // mode 0: h+stats, 1: pool
  __shared__ float2 bembS[24 * 64];
  const float2* bemb2 = reinterpret_cast<const float2*>(bemb);
  for (int i = threadIdx.x; i < 24 * 64; i += 256) bembS[i] = bemb2[i];
  const int wid = threadIdx.x >> 6;
  const int lane = threadIdx.x & 63;
  float2 rt = *reinterpret_cast<const float2*>(&root[2 * lane]);
  float ls0 = 0, ls1 = 0, lq0 = 0, lq1 = 0;
  const int wv = blockIdx.x * 4 + wid;
  const int n0 = wv * CHUNK;
  const int n1 = min(n0 + CHUNK, NN);
  int curg = -1;
  float pg0 = 0.f, pg1 = 0.f;
  __syncthreads();
  for (int n = n0; n < n1; ++n) {
    int k0 = off[n], k1 = off[n + 1];
    float acc0 = 0.f, acc1 = 0.f;
    int k = k0;
    for (; k + 3 < k1; k += 4) {
      int2 e0 = edata[k], e1 = edata[k + 1], e2 = edata[k + 2],
           e3 = edata[k + 3];
      PROC(e0) PROC(e1) PROC(e2) PROC(e3)
    }
    for (; k < k1; ++k) {
      int2 e0 = edata[k];
      PROC(e0)
    }
    float dr = degrecip[n];
    float2 hs = __half22float2(hl2[n * 64 + lane]);
    float v0 = acc0 + fmaxf(hs.x + rt.x, 0.f) * dr;
    float v1 = acc1 + fmaxf(hs.y + rt.y, 0.f) * dr;
    if (mode == 0) {
      h2[n * 64 + lane] = __floats2half2_rn(v0, v1);
      ls0 += v0; ls1 += v1;
      lq0 += v0 * v0; lq1 += v1 * v1;
    } else {
      int g = batch[n];
      if (g != curg) {
        if (curg >= 0) {
          atomAddF(&hg[curg * DD + 2 * lane], pg0);
          atomAddF(&hg[curg * DD + 2 * lane + 1], pg1);
        }
        curg = g;
        pg0 = v0; pg1 = v1;
      } else {
        pg0 += v0; pg1 += v1;
      }
    }
  }
  if (mode == 1) {
    if (curg >= 0) {
      atomAddF(&hg[curg * DD + 2 * lane], pg0);
      atomAddF(&hg[curg * DD + 2 * lane + 1], pg1);
    }
    return;
  }
  __shared__ float s0[DD], s1[DD];
  const int d0 = 2 * lane, d1 = 2 * lane + 1;
  if (wid == 0) {
    s0[d0] = ls0; s0[d1] = ls1;
    s1[d0] = lq0; s1[d1] = lq1;
  }
  __syncthreads();
#pragma unroll
  for (int w = 1; w < 4; ++w) {
    if (wid == w) {
      s0[d0] += ls0; s0[d1] += ls1;
      s1[d0] += lq0; s1[d1] += lq1;
    }
    __syncthreads();
  }
  if (threadIdx.x < DD) {
    atomAddF(&bn_sum[threadIdx.x], s0[threadIdx.x]);
    atomAddF(&bn_sq[threadIdx.x], s1[threadIdx.x]);
  }
}

__global__ __launch_bounds__(128) void bn_finalize_kernel(
    const float* __restrict__ bn_sum, const float* __restrict__ bn_sq,
    const float* __restrict__ gamma, const float* __restrict__ beta,
    float* __restrict__ scale, float* __restrict__ shift) {
  int d = threadIdx.x;
  float mu = bn_sum[d] / (float)NN;
  float var = bn_sq[d] / (float)NN - mu * mu;
  float inv = rsqrtf(var + BN_EPS);
  float sc = gamma[d] * inv;
  scale[d] = sc;
  shift[d] = beta[d] - mu * sc;
}

// ---------------- MLP on pooled features ----------------

__global__ __launch_bounds__(128) void mlp_kernel(
    const float* __restrict__ hg, const int* __restrict__ gstart,
    const float* __restrict__ W1, const float* __restrict__ b1,
    const float* __restrict__ W2, const float* __restrict__ b2,
    float* __restrict__ out) {
  int g = blockIdx.x, t = threadIdx.x;
  float cnt = fmaxf((float)(gstart[g + 1] - gstart[g]), 1.f);
  __shared__ float row[DD], t1[DD];
  row[t] = fmaxf(hg[g * DD + t] / cnt, 0.f);
  __syncthreads();
  float a1v = b1[t];
  for (int k = 0; k < DD; ++k) a1v = fmaf(row[k], W1[k * DD + t], a1v);
  t1[t] = fmaxf(a1v, 0.f);
  __syncthreads();
  if (t < NT) {
    float a2 = b2[t];
    for (int k = 0; k < DD; ++k) a2 = fmaf(t1[k], W2[k * NT + t], a2);
    out[g * NT + t] = a2;
  }
}

extern "C" void kernel_launch(void* const* d_in, const int* in_sizes, int n_in,
                              void* d_out, int out_size, void* d_ws,
                              size_t ws_size, hipStream_t stream) {
  const int* x = (const int*)d_in[0];
  const int* edge_index = (const int*)d_in[1];
  const int* batch = (const int*)d_in[2];
  const int* edge_attr = (const int*)d_in[3];
  const float* atom_emb = (const float*)d_in[4];
  const float* W = (const float*)d_in[5];
  const float* b = (const float*)d_in[6];
  const float* root = (const float*)d_in[7];
  const float* bond_emb = (const float*)d_in[8];
  const float* gamma = (const float*)d_in[9];
  const float* beta = (const float*)d_in[10];
  const float* W1 = (const float*)d_in[11];
  const float* b1 = (const float*)d_in[12];
  const float* W2 = (const float*)d_in[13];
  const float* b2 = (const float*)d_in[14];
  float* out = (float*)d_out;

  char* ws = (char*)d_ws;
  size_t off_b = 0;
  auto alloc = [&](size_t bytes) {
    char* p = ws + off_b;
    off_b += (bytes + 255) & ~size_t(255);
    return p;
  };
  __half* h = (__half*)alloc(sizeof(__half) * NN * DD);
  __half* hl = (__half*)alloc(sizeof(__half) * NN * DD);
  int2* edata = (int2*)alloc(sizeof(int2) * NE);
  float* degrecip = (float*)alloc(sizeof(float) * NN);
  float* dinv = (float*)alloc(sizeof(float) * NN);
  int* off = (int*)alloc(sizeof(int) * (NN + 1));
  int* bsum = (int*)alloc(sizeof(int) * 128);
  float* bsc = (float*)alloc(sizeof(float) * DD);
  float* bsh = (float*)alloc(sizeof(float) * DD);
  int* gstart = (int*)alloc(sizeof(int) * (NG + 1));
  __half* Wf = (__half*)alloc(sizeof(__half) * NL * DD * DD);
  __half* aemb16 = (__half*)alloc(sizeof(__half) * 9 * 64 * DD);
  // ---- contiguous zero region ----
  char* zstart = ws + off_b;
  int* degcnt = (int*)alloc(sizeof(int) * NN);
  int* incnt = (int*)alloc(sizeof(int) * NN);
  int* cursor = (int*)alloc(sizeof(int) * NN);
  float* hg = (float*)alloc(sizeof(float) * NG * DD);
  float* bnS = (float*)alloc(sizeof(float) * NL * DD);
  float* bnQ = (float*)alloc(sizeof(float) * NL * DD);
  size_t zbytes = (ws + off_b) - zstart;

  hipMemsetAsync(zstart, 0, zbytes, stream);

  edge_count_kernel<<<(NE / 4 + 255) / 256, 256, 0, stream>>>(edge_index,
                                                              degcnt, incnt);
  tables_kernel<<<(9 * 64 * 32 + 255) / 256, 256, 0, stream>>>(
      W, Wf, atom_emb, aemb16, batch, gstart);
  atom_encoder_kernel<<<(NN * 16 + 255) / 256, 256, 0, stream>>>(x, aemb16, h);

  const int nb = (NN + SCAN_B - 1) / SCAN_B;  // 98
  scan1_kernel<<<nb, 256, 0, stream>>>(incnt, off, bsum, degcnt, degrecip,
                                       dinv, NN);
  scan2_kernel<<<1, 128, 0, stream>>>(bsum, nb);
  scan3_kernel<<<(NN + 255) / 256, 256, 0, stream>>>(off, bsum, NN, NE);
  csr_fill_kernel<<<(NE + 255) / 256, 256, 0, stream>>>(edge_index, edge_attr,
                                                        dinv, off, cursor, edata);

  const int GB = (NN + 4 * CHUNK - 1) / (4 * CHUNK);  // 1924 blocks
  for (int l = 0; l < NL; ++l) {
    gemm_mfma_kernel<<<(NN + 63) / 64, 256, 0, stream>>>(
        h, Wf + l * DD * DD, b + l * DD, bsc, bsh, l > 0 ? 1 : 0, hl);
    int mode = (l < NL - 1) ? 0 : 1;
    gather_update_kernel<<<GB, 256, 0, stream>>>(
        off, edata, (const __half2*)hl, bond_emb + l * 3 * 8 * DD,
        root + l * DD, degrecip, batch, (__half2*)h, hg, bnS + l * DD,
        bnQ + l * DD, mode);
    if (mode == 0) {
      bn_finalize_kernel<<<1, DD, 0, stream>>>(bnS + l * DD, bnQ + l * DD,
                                               gamma + l * DD, beta + l * DD,
                                               bsc, bsh);
    }
  }

  mlp_kernel<<<NG, DD, 0, stream>>>(hg, gstart, W1, b1, W2, b2, out);
}